// Round 1
// baseline (675.940 us; speedup 1.0000x reference)
//
#include <hip/hip_runtime.h>

// S4D forward as a diagonal complex SSM scan.
// B=32,H=256,L=4096,N=64. 8 threads/sequence x 8 modes/thread.
// Per-wave double-buffered LDS staging of u via global_load_lds (width 16),
// counted vmcnt waits, no block barriers (waves are independent).

#define Bb 32
#define Hh 256
#define Ll 4096
#define Nn 64
#define Tt 64          // chunk length (floats) per sequence
#define NCHUNK (Ll / Tt)
#define SPB 32         // sequences per block (256 threads / 8)

typedef float f32x4 __attribute__((ext_vector_type(4)));

__global__ __launch_bounds__(256)
void s4d_scan(const float* __restrict__ u, const float* __restrict__ lr_,
              const float* __restrict__ li_, const float* __restrict__ cv,
              const float* __restrict__ dv, const float* __restrict__ dl,
              float* __restrict__ y)
{
  // lds[buf][row(=seqLocal)][64 floats], 16B slots swizzled by (row&7)
  __shared__ float lds[2 * SPB * Tt];

  const int tid  = threadIdx.x;
  const int wave = tid >> 6;     // 0..3
  const int lane = tid & 63;
  const int sLoc = tid >> 3;     // 0..31 sequence within block
  const int grp  = tid & 7;      // mode group within sequence
  const int seqBase = blockIdx.x * SPB;
  const int seq  = seqBase + sLoc;       // = b*H + h
  const int h    = seq & (Hh - 1);

  // ---- per-thread mode parameters: w = exp(dt*A), coef = C*(w-1)/A ----
  float wr[8], wi[8], cr[8], ci[8], sr[8], si[8];
  {
    const float dt = expf(dl[h]);
    #pragma unroll
    for (int k = 0; k < 8; ++k) {
      const int n = grp * 8 + k;
      const float Ar = fminf(lr_[h * Nn + n], -1e-4f);
      const float Ai = li_[h * Nn + n];
      const float dAr = dt * Ar, dAi = dt * Ai;
      const float er = expf(dAr);
      const float wwr = er * cosf(dAi);
      const float wwi = er * sinf(dAi);
      wr[k] = wwr; wi[k] = wwi;
      const float nr = wwr - 1.0f, ni = wwi;      // w - 1
      const float inv = 1.0f / (Ar * Ar + Ai * Ai);
      const float qr = (nr * Ar + ni * Ai) * inv; // (w-1)/A
      const float qi = (ni * Ar - nr * Ai) * inv;
      const float c0 = cv[(h * Nn + n) * 2 + 0];
      const float c1 = cv[(h * Nn + n) * 2 + 1];
      cr[k] = c0 * qr - c1 * qi;                  // coef = C*(w-1)/A
      ci[k] = c0 * qi + c1 * qr;
      sr[k] = 0.0f; si[k] = 0.0f;
    }
  }
  const float dh = dv[h];

  // ---- staging source addresses (pre-swizzled so linear LDS dest = swizzled layout)
  // instr j in {0,1}: lane l -> row = wave*8 + j*4 + (l>>4), slot q' = l&15,
  // holds logical quad q = q' ^ (row&7).
  const int sl0 = wave * 8 + (lane >> 4);
  const int sl1 = sl0 + 4;
  const int q0  = (lane & 15) ^ (sl0 & 7);
  const int q1  = (lane & 15) ^ (sl1 & 7);
  const float* g0 = u + (size_t)(seqBase + sl0) * Ll + q0 * 4;
  const float* g1 = u + (size_t)(seqBase + sl1) * Ll + q1 * 4;

  #define STAGE(c, buf) do { \
    __builtin_amdgcn_global_load_lds( \
      (const __attribute__((address_space(1))) void*)(g0 + (size_t)(c) * Tt), \
      (__attribute__((address_space(3))) void*)(&lds[(buf) * (SPB * Tt) + wave * 512]), \
      16, 0, 0); \
    __builtin_amdgcn_global_load_lds( \
      (const __attribute__((address_space(1))) void*)(g1 + (size_t)(c) * Tt), \
      (__attribute__((address_space(3))) void*)(&lds[(buf) * (SPB * Tt) + wave * 512 + 256]), \
      16, 0, 0); \
  } while (0)

  STAGE(0, 0);
  STAGE(1, 1);

  const int sw = sLoc & 7;
  float* yp0 = y + (size_t)seq * Ll;

  for (int c = 0; c < NCHUNK; ++c) {
    // wait for this chunk's 2 staging loads (leave next chunk's 2 in flight)
    if (c < NCHUNK - 1) { asm volatile("s_waitcnt vmcnt(2)" ::: "memory"); }
    else                { asm volatile("s_waitcnt vmcnt(0)" ::: "memory"); }

    const float* rb = &lds[(c & 1) * (SPB * Tt) + sLoc * Tt];
    float* yp = yp0 + c * Tt;

    #pragma unroll 4
    for (int q = 0; q < 16; ++q) {
      const f32x4 uq = *(const f32x4*)(rb + ((q ^ sw) << 2)); // broadcast to 8 lanes
      f32x4 y4;
      #pragma unroll
      for (int t = 0; t < 4; ++t) {
        const float uv = uq[t];
        float acc = 0.0f;
        #pragma unroll
        for (int k = 0; k < 8; ++k) {
          // s' = w*s + u   (u real)
          const float nsr = fmaf(-wi[k], si[k], fmaf(wr[k], sr[k], uv));
          const float nsi = fmaf(wi[k], sr[k], wr[k] * si[k]);
          sr[k] = nsr; si[k] = nsi;
          // y += Re(coef * s')
          acc = fmaf(cr[k], nsr, acc);
          acc = fmaf(-ci[k], nsi, acc);
        }
        // reduce over the 8 lanes of this sequence group
        acc += __shfl_xor(acc, 1);
        acc += __shfl_xor(acc, 2);
        acc += __shfl_xor(acc, 4);
        y4[t] = fmaf(dh, uv, acc);
      }
      if (grp == 0) *(f32x4*)(yp + (q << 2)) = y4;
    }

    if (c + 2 < NCHUNK) {
      // all ds_reads of this buffer retired before its async overwrite
      asm volatile("s_waitcnt lgkmcnt(0)" ::: "memory");
      STAGE(c + 2, c & 1);
    }
  }
  #undef STAGE
}

extern "C" void kernel_launch(void* const* d_in, const int* in_sizes, int n_in,
                              void* d_out, int out_size, void* d_ws, size_t ws_size,
                              hipStream_t stream)
{
  const float* u  = (const float*)d_in[0];
  const float* lr = (const float*)d_in[1];
  const float* li = (const float*)d_in[2];
  const float* cv = (const float*)d_in[3];
  const float* dv = (const float*)d_in[4];
  const float* dl = (const float*)d_in[5];
  float* yo = (float*)d_out;

  s4d_scan<<<dim3((Bb * Hh) / SPB), dim3(256), 0, stream>>>(u, lr, li, cv, dv, dl, yo);
}

// Round 3
// 387.258 us; speedup vs baseline: 1.7455x; 1.7455x over previous
//
#include <hip/hip_runtime.h>

// S4D as chunked linear recurrence with MFMA (bf16 in / fp32 acc).
// Per h (workgroup): per chunk c of T=64 steps, with 32 batch cols:
//   Y[t][b]  = sum_tau M[t][tau] U[tau][b]  +  Re(E[t][.] . S[.][b])
//   s'[n]    = w_n^64 * s[n] + sum_tau w_n^{63-tau} U[tau][b]   (G matmul)
// M,E,G are per-h constants kept in A-frag registers for all 64 chunks.

#define Bb 32
#define Hh 256
#define Ll 4096
#define Nn 64
#define Tt 64
#define NCH (Ll / Tt)
#define PADK 136   // shorts per S_lds row (128 + 8 pad) -> conflict-optimal

typedef float  f32x4  __attribute__((ext_vector_type(4)));
typedef short  bf16x8 __attribute__((ext_vector_type(8)));
typedef short  s16x4  __attribute__((ext_vector_type(4)));

__device__ inline short f2bf(float f) {            // RNE float->bf16
  unsigned x = __float_as_uint(f);
  unsigned r = x + 0x7fffu + ((x >> 16) & 1u);
  return (short)(r >> 16);
}

__global__ __launch_bounds__(256, 1)
void s4d_mfma(const float* __restrict__ u, const float* __restrict__ lr_,
              const float* __restrict__ li_, const float* __restrict__ cv,
              const float* __restrict__ dv, const float* __restrict__ dl,
              float* __restrict__ y)
{
  __shared__ float tab[4 * Nn];     // dAr | dAi | coef_r | coef_i
  __shared__ float kpart[4][Tt];
  __shared__ float ktab[Tt];
  __shared__ short S_lds[32 * PADK];  // [col=b][k=0..127 interleaved re/im]

  const int h   = blockIdx.x;
  const int tid = threadIdx.x;
  const int w   = tid >> 6;     // wave 0..3
  const int l   = tid & 63;
  const int l16 = l & 15;
  const int lg  = l >> 4;       // k-group / C-row group

  for (int i = tid; i < 32 * PADK; i += 256) S_lds[i] = 0;

  // ---- per-mode params -> LDS table ----
  if (tid < Nn) {
    const int n = tid;
    const float dt  = expf(dl[h]);
    const float Ar  = fminf(lr_[h * Nn + n], -1e-4f);
    const float Ai  = li_[h * Nn + n];
    const float dAr = dt * Ar, dAi = dt * Ai;
    const float er  = expf(dAr);
    const float wwr = er * cosf(dAi), wwi = er * sinf(dAi);
    const float inv = 1.0f / (Ar * Ar + Ai * Ai);
    const float nr  = wwr - 1.0f, ni = wwi;
    const float qr  = (nr * Ar + ni * Ai) * inv;   // (w-1)/A
    const float qi  = (ni * Ar - nr * Ai) * inv;
    const float c0  = cv[(h * Nn + n) * 2 + 0];
    const float c1  = cv[(h * Nn + n) * 2 + 1];
    tab[n]       = dAr;
    tab[64 + n]  = dAi;
    tab[128 + n] = c0 * qr - c1 * qi;              // coef = C*(w-1)/A
    tab[192 + n] = c0 * qi + c1 * qr;
  }
  __syncthreads();

  // ---- U load pointers + issue first chunk's loads (overlap prologue) ----
  const float* uptr[2];
  #pragma unroll
  for (int q = 0; q < 2; ++q)
    uptr[q] = u + ((size_t)(16 * q + l16) * Hh + h) * Ll + 8 * lg;

  f32x4 up[2][2][2];   // [colTile q][kHalf][16B half]
  #pragma unroll
  for (int q = 0; q < 2; ++q)
    #pragma unroll
    for (int kh = 0; kh < 2; ++kh) {
      const float* p = uptr[q] + 32 * kh;
      up[q][kh][0] = *(const f32x4*)p;
      up[q][kh][1] = *(const f32x4*)(p + 4);
    }

  // ---- kernel taps K[j] = Re sum_n coef_n w_n^j ----
  {
    const int j = tid & 63, part = tid >> 6;
    float acc = 0.f;
    for (int n = part * 16; n < part * 16 + 16; ++n) {
      const float m = expf((float)j * tab[n]);
      const float a = (float)j * tab[64 + n];
      acc += tab[128 + n] * (m * cosf(a)) - tab[192 + n] * (m * sinf(a));
    }
    kpart[part][j] = acc;
  }
  __syncthreads();
  if (tid < 64) ktab[tid] = kpart[0][tid] + kpart[1][tid] + kpart[2][tid] + kpart[3][tid];
  __syncthreads();

  // ---- constant matrices into A-frag registers ----
  const int trow = 16 * w + l16;        // A-operand row for M/E (= t_local)
  const float dval = dv[h];
  bf16x8 Mf[2], Ef[4], Gf[2][2];
  #pragma unroll
  for (int kh = 0; kh < 2; ++kh)
    #pragma unroll
    for (int e = 0; e < 8; ++e) {
      const int tau = 8 * lg + e + 32 * kh;
      const int j = trow - tau;
      float v = 0.f;
      if (j >= 0) v = ktab[j] + (j == 0 ? dval : 0.f);
      Mf[kh][e] = f2bf(v);
    }
  #pragma unroll
  for (int kf = 0; kf < 4; ++kf)
    #pragma unroll
    for (int e = 0; e < 8; ++e) {
      const int cidx = 8 * lg + e + 32 * kf;   // k = 2n (Re) / 2n+1 (Im)
      const int n = cidx >> 1;
      const float p1 = (float)(trow + 1);
      const float m  = expf(p1 * tab[n]);
      const float a  = p1 * tab[64 + n];
      const float re = m * cosf(a), im = m * sinf(a);
      const float pr = tab[128 + n] * re - tab[192 + n] * im;
      const float pi = tab[128 + n] * im + tab[192 + n] * re;
      Ef[kf][e] = f2bf((cidx & 1) ? -pi : pr);
    }
  #pragma unroll
  for (int p = 0; p < 2; ++p)
    #pragma unroll
    for (int kh = 0; kh < 2; ++kh)
      #pragma unroll
      for (int e = 0; e < 8; ++e) {
        const int r   = 32 * w + 16 * p + l16;  // state row (2n / 2n+1)
        const int n   = r >> 1;
        const int tau = 8 * lg + e + 32 * kh;
        const float pw = (float)(63 - tau);
        const float m  = expf(pw * tab[n]);
        const float a  = pw * tab[64 + n];
        Gf[p][kh][e] = f2bf((r & 1) ? m * sinf(a) : m * cosf(a));
      }
  // carry multiplier w^64 for this lane's C-frag rows 32w+16p+4lg+{0..3}
  float Wr[2][2], Wi[2][2];
  #pragma unroll
  for (int p = 0; p < 2; ++p) {
    const int n0 = (32 * w + 16 * p + 4 * lg) >> 1;
    #pragma unroll
    for (int mm = 0; mm < 2; ++mm) {
      const float m = expf(64.f * tab[n0 + mm]);
      const float a = 64.f * tab[64 + n0 + mm];
      Wr[p][mm] = m * cosf(a);
      Wi[p][mm] = m * sinf(a);
    }
  }

  f32x4 sf[2][2] = {};   // carry state, C-frag layout, fp32
  float* yptr[2];
  #pragma unroll
  for (int q = 0; q < 2; ++q)
    yptr[q] = y + ((size_t)(16 * q + l16) * Hh + h) * Ll + 16 * w + 4 * lg;

  __syncthreads();   // S_lds zeros + ktab visible

  const f32x4 zf = {0.f, 0.f, 0.f, 0.f};

  for (int c = 0; c < NCH; ++c) {
    // ---- convert current U to bf16 B-frags ----
    bf16x8 Uf[2][2];
    #pragma unroll
    for (int q = 0; q < 2; ++q)
      #pragma unroll
      for (int kh = 0; kh < 2; ++kh)
        #pragma unroll
        for (int e = 0; e < 4; ++e) {
          Uf[q][kh][e]     = f2bf(up[q][kh][0][e]);
          Uf[q][kh][4 + e] = f2bf(up[q][kh][1][e]);
        }
    // ---- issue next chunk's U loads (stay in flight across barriers) ----
    if (c + 1 < NCH) {
      #pragma unroll
      for (int q = 0; q < 2; ++q)
        #pragma unroll
        for (int kh = 0; kh < 2; ++kh) {
          const float* p = uptr[q] + (size_t)(c + 1) * Tt + 32 * kh;
          up[q][kh][0] = *(const f32x4*)p;
          up[q][kh][1] = *(const f32x4*)(p + 4);
        }
    }
    // ---- Y = E x S(prev) + M x U ; store ----
    #pragma unroll
    for (int q = 0; q < 2; ++q) {
      f32x4 yf = zf;
      const short* sb = &S_lds[(16 * q + l16) * PADK + 8 * lg];
      #pragma unroll
      for (int kf = 0; kf < 4; ++kf) {
        const bf16x8 sfr = *(const bf16x8*)(sb + 32 * kf);
        yf = __builtin_amdgcn_mfma_f32_16x16x32_bf16(Ef[kf], sfr, yf, 0, 0, 0);
      }
      #pragma unroll
      for (int kh = 0; kh < 2; ++kh)
        yf = __builtin_amdgcn_mfma_f32_16x16x32_bf16(Mf[kh], Uf[q][kh], yf, 0, 0, 0);
      *(f32x4*)(yptr[q] + (size_t)c * Tt) = yf;
    }
    // ---- gather g = G x U ----
    f32x4 gf[2][2];
    #pragma unroll
    for (int p = 0; p < 2; ++p)
      #pragma unroll
      for (int q = 0; q < 2; ++q) {
        f32x4 g = zf;
        #pragma unroll
        for (int kh = 0; kh < 2; ++kh)
          g = __builtin_amdgcn_mfma_f32_16x16x32_bf16(Gf[p][kh], Uf[q][kh], g, 0, 0, 0);
        gf[p][q] = g;
      }
    // all S reads of this chunk retired before overwrite
    asm volatile("s_waitcnt lgkmcnt(0)" ::: "memory");
    __builtin_amdgcn_s_barrier();
    // ---- carry update s' = W*s + g (fp32), write bf16 S for next chunk ----
    #pragma unroll
    for (int p = 0; p < 2; ++p)
      #pragma unroll
      for (int q = 0; q < 2; ++q) {
        const float sr0 = sf[p][q][0], si0 = sf[p][q][1];
        const float sr1 = sf[p][q][2], si1 = sf[p][q][3];
        const float a0 = fmaf(Wr[p][0], sr0, fmaf(-Wi[p][0], si0, gf[p][q][0]));
        const float b0 = fmaf(Wi[p][0], sr0, fmaf( Wr[p][0], si0, gf[p][q][1]));
        const float a1 = fmaf(Wr[p][1], sr1, fmaf(-Wi[p][1], si1, gf[p][q][2]));
        const float b1 = fmaf(Wi[p][1], sr1, fmaf( Wr[p][1], si1, gf[p][q][3]));
        sf[p][q][0] = a0; sf[p][q][1] = b0; sf[p][q][2] = a1; sf[p][q][3] = b1;
        s16x4 pk = { f2bf(a0), f2bf(b0), f2bf(a1), f2bf(b1) };
        *(s16x4*)(&S_lds[(16 * q + l16) * PADK + 32 * w + 16 * p + 4 * lg]) = pk;
      }
    asm volatile("s_waitcnt lgkmcnt(0)" ::: "memory");
    __builtin_amdgcn_s_barrier();
  }
}

extern "C" void kernel_launch(void* const* d_in, const int* in_sizes, int n_in,
                              void* d_out, int out_size, void* d_ws, size_t ws_size,
                              hipStream_t stream)
{
  const float* u  = (const float*)d_in[0];
  const float* lr = (const float*)d_in[1];
  const float* li = (const float*)d_in[2];
  const float* cv = (const float*)d_in[3];
  const float* dv = (const float*)d_in[4];
  const float* dl = (const float*)d_in[5];
  float* yo = (float*)d_out;

  s4d_mfma<<<dim3(Hh), dim3(256), 0, stream>>>(u, lr, li, cv, dv, dl, yo);
}

// Round 5
// 295.703 us; speedup vs baseline: 2.2859x; 1.3096x over previous
//
#include <hip/hip_runtime.h>

// S4D chunked recurrence, register-resident state, zero barriers in main loop.
// Per h (1 WG of 4 waves): wave w owns b-tile qb=w&1 (16 cols) and t-half th=w>>1.
// Per chunk c (T=64 steps):
//   Y[t][b] = sum_tau M[t][tau] U[tau][b] + sum_k E[t][k] S[k][b]
//   S'      = W o S + G x U            (all 128 state rows per wave, in regs)
// E's column order is chosen so G's C-frag output IS E's B-frag input (no permute).

#define Hh 256
#define Ll 4096
#define Nn 64
#define Tt 64
#define NCH (Ll / Tt)

typedef float  f32x4  __attribute__((ext_vector_type(4)));
typedef short  bf16x8 __attribute__((ext_vector_type(8)));

__device__ inline short f2bf(float f) {            // RNE float->bf16
  unsigned x = __float_as_uint(f);
  unsigned r = x + 0x7fffu + ((x >> 16) & 1u);
  return (short)(r >> 16);
}
__device__ inline unsigned pk2(float a, float b) { // pack 2 f32 -> 2 bf16
  return (unsigned)(unsigned short)f2bf(a) | ((unsigned)(unsigned short)f2bf(b) << 16);
}

__global__ __launch_bounds__(256, 1)
void s4d_reg(const float* __restrict__ u, const float* __restrict__ lr_,
             const float* __restrict__ li_, const float* __restrict__ cv,
             const float* __restrict__ dv, const float* __restrict__ dl,
             float* __restrict__ y)
{
  // prologue-only LDS: per-mode params + power table w_n^j, j=0..64
  __shared__ float tbr[Nn], tbi[Nn], cfr[Nn], cfi[Nn];
  __shared__ float ptr_[Tt + 1][Nn];
  __shared__ float pti_[Tt + 1][Nn];
  __shared__ float kpart[4][Tt];
  __shared__ float ktab[Tt];

  const int h   = blockIdx.x;
  const int tid = threadIdx.x;
  const int w   = tid >> 6;
  const int l   = tid & 63;
  const int l16 = l & 15;
  const int lg  = l >> 4;
  const int qb  = w & 1;      // b-tile (16 cols)
  const int th  = w >> 1;     // t-half (32 rows)

  // ---- per-mode params ----
  if (tid < Nn) {
    const int n = tid;
    const float dt  = expf(dl[h]);
    const float Ar  = fminf(lr_[h * Nn + n], -1e-4f);
    const float Ai  = li_[h * Nn + n];
    const float dAr = dt * Ar, dAi = dt * Ai;
    const float er  = expf(dAr);
    const float wwr = er * cosf(dAi), wwi = er * sinf(dAi);
    const float inv = 1.0f / (Ar * Ar + Ai * Ai);
    const float nr  = wwr - 1.0f, ni = wwi;
    const float qr  = (nr * Ar + ni * Ai) * inv;   // (w-1)/A
    const float qi  = (ni * Ar - nr * Ai) * inv;
    const float c0  = cv[(h * Nn + n) * 2 + 0];
    const float c1  = cv[(h * Nn + n) * 2 + 1];
    tbr[n] = dAr; tbi[n] = dAi;
    cfr[n] = c0 * qr - c1 * qi;                    // coef = C*(w-1)/A
    cfi[n] = c0 * qi + c1 * qr;
  }
  __syncthreads();

  // ---- power table: w_n^j = exp(j*dAr) * (cos, sin)(j*dAi) ----
  for (int idx = tid; idx < (Tt + 1) * Nn; idx += 256) {
    const int j = idx >> 6, n = idx & 63;
    const float m = expf((float)j * tbr[n]);
    float sa, ca;
    sincosf((float)j * tbi[n], &sa, &ca);
    ptr_[j][n] = m * ca;
    pti_[j][n] = m * sa;
  }
  __syncthreads();

  // ---- kernel taps K[j] = Re sum_n coef_n w_n^j ----
  {
    const int j = tid & 63, part = tid >> 6;
    float acc = 0.f;
    for (int n = part * 16; n < part * 16 + 16; ++n)
      acc += cfr[n] * ptr_[j][n] - cfi[n] * pti_[j][n];
    kpart[part][j] = acc;
  }
  __syncthreads();
  if (tid < Tt) ktab[tid] = kpart[0][tid] + kpart[1][tid] + kpart[2][tid] + kpart[3][tid];
  __syncthreads();

  // ---- constant fragments (A-operands, bf16) ----
  const float dval = dv[h];
  bf16x8 Mf[2][2];   // [t-tile][kh]   M[t][tau]
  bf16x8 Ef[2][4];   // [t-tile][kf]   E[t][sigma(kf,lg,e)]
  bf16x8 Gf[8][2];   // [row-tile][kh] G[state][tau]
  float  Wr[8][2], Wi[8][2];

  #pragma unroll
  for (int tt = 0; tt < 2; ++tt) {
    const int t = 32 * th + 16 * tt + l16;
    #pragma unroll
    for (int kh = 0; kh < 2; ++kh)
      #pragma unroll
      for (int e = 0; e < 8; ++e) {
        const int tau = 32 * kh + 8 * lg + e;
        const int j = t - tau;
        Mf[tt][kh][e] = f2bf(j < 0 ? 0.f : (ktab[j] + (j == 0 ? dval : 0.f)));
      }
    #pragma unroll
    for (int kf = 0; kf < 4; ++kf)
      #pragma unroll
      for (int e = 0; e < 8; ++e) {
        const int sg = 32 * kf + 16 * (e >> 2) + 4 * lg + (e & 3);  // state index
        const int n  = sg >> 1;
        const float pr = ptr_[t + 1][n], pi = pti_[t + 1][n];
        const float rr = cfr[n] * pr - cfi[n] * pi;   // Re(coef w^{t+1})
        const float ii = cfr[n] * pi + cfi[n] * pr;   // Im(coef w^{t+1})
        Ef[tt][kf][e] = f2bf((sg & 1) ? -ii : rr);
      }
  }
  #pragma unroll
  for (int rt = 0; rt < 8; ++rt) {
    const int r = 16 * rt + l16;          // state row (2n=Re, 2n+1=Im)
    const int n = r >> 1;
    #pragma unroll
    for (int kh = 0; kh < 2; ++kh)
      #pragma unroll
      for (int e = 0; e < 8; ++e) {
        const int p = 63 - (32 * kh + 8 * lg + e);
        Gf[rt][kh][e] = f2bf((r & 1) ? pti_[p][n] : ptr_[p][n]);
      }
    #pragma unroll
    for (int m = 0; m < 2; ++m) {
      const int nn = 8 * rt + 2 * lg + m; // this lane's C-frag complex modes
      Wr[rt][m] = ptr_[Tt][nn];
      Wi[rt][m] = pti_[Tt][nn];
    }
  }

  // ---- state (bf16 packed, 2 words per row-tile) ----
  unsigned Sw[16];
  #pragma unroll
  for (int i = 0; i < 16; ++i) Sw[i] = 0u;

  const float* pu  = u + ((size_t)(16 * qb + l16) * Hh + h) * Ll + 8 * lg;
  float*       py0 = y + ((size_t)(16 * qb + l16) * Hh + h) * Ll + 32 * th + 4 * lg;

  f32x4 upA[4], upB[4];
  #pragma unroll
  for (int kh = 0; kh < 2; ++kh) {
    upA[2 * kh] = *(const f32x4*)(pu + 32 * kh);
    upA[2 * kh + 1] = *(const f32x4*)(pu + 32 * kh + 4);
    upB[2 * kh] = *(const f32x4*)(pu + Tt + 32 * kh);
    upB[2 * kh + 1] = *(const f32x4*)(pu + Tt + 32 * kh + 4);
  }

  const f32x4 zf = {0.f, 0.f, 0.f, 0.f};

#define BODY(c, UP)                                                            \
  {                                                                            \
    bf16x8 Uf[2];                                                              \
    _Pragma("unroll")                                                          \
    for (int kh = 0; kh < 2; ++kh) {                                           \
      bf16x8 t;                                                                \
      _Pragma("unroll")                                                        \
      for (int e2 = 0; e2 < 4; ++e2) {                                         \
        t[e2]     = f2bf(UP[2 * kh][e2]);                                      \
        t[4 + e2] = f2bf(UP[2 * kh + 1][e2]);                                  \
      }                                                                        \
      Uf[kh] = t;                                                              \
    }                                                                          \
    if ((c) + 2 < NCH) {                                                       \
      _Pragma("unroll")                                                        \
      for (int kh = 0; kh < 2; ++kh) {                                         \
        UP[2 * kh]     = *(const f32x4*)(pu + ((c) + 2) * Tt + 32 * kh);       \
        UP[2 * kh + 1] = *(const f32x4*)(pu + ((c) + 2) * Tt + 32 * kh + 4);   \
      }                                                                        \
    }                                                                          \
    _Pragma("unroll")                                                          \
    for (int tt = 0; tt < 2; ++tt) {                                           \
      f32x4 yv = zf;                                                           \
      _Pragma("unroll")                                                        \
      for (int kf = 0; kf < 4; ++kf) {                                         \
        bf16x8 sb;                                                             \
        unsigned* sbw = (unsigned*)&sb;                                        \
        sbw[0] = Sw[4 * kf]; sbw[1] = Sw[4 * kf + 1];                          \
        sbw[2] = Sw[4 * kf + 2]; sbw[3] = Sw[4 * kf + 3];                      \
        yv = __builtin_amdgcn_mfma_f32_16x16x32_bf16(Ef[tt][kf], sb, yv, 0, 0, 0); \
      }                                                                        \
      _Pragma("unroll")                                                        \
      for (int kh = 0; kh < 2; ++kh)                                           \
        yv = __builtin_amdgcn_mfma_f32_16x16x32_bf16(Mf[tt][kh], Uf[kh], yv, 0, 0, 0); \
      *(f32x4*)(py0 + (size_t)(c) * Tt + 16 * tt) = yv;                        \
    }                                                                          \
    _Pragma("unroll")                                                          \
    for (int rt = 0; rt < 8; ++rt) {                                           \
      f32x4 g = zf;                                                            \
      g = __builtin_amdgcn_mfma_f32_16x16x32_bf16(Gf[rt][0], Uf[0], g, 0, 0, 0); \
      g = __builtin_amdgcn_mfma_f32_16x16x32_bf16(Gf[rt][1], Uf[1], g, 0, 0, 0); \
      const unsigned w0 = Sw[2 * rt], w1 = Sw[2 * rt + 1];                     \
      const float s0r = __uint_as_float(w0 << 16);                             \
      const float s0i = __uint_as_float(w0 & 0xffff0000u);                     \
      const float s1r = __uint_as_float(w1 << 16);                             \
      const float s1i = __uint_as_float(w1 & 0xffff0000u);                     \
      const float nr0 = fmaf(Wr[rt][0], s0r, fmaf(-Wi[rt][0], s0i, g[0]));     \
      const float ni0 = fmaf(Wi[rt][0], s0r, fmaf( Wr[rt][0], s0i, g[1]));     \
      const float nr1 = fmaf(Wr[rt][1], s1r, fmaf(-Wi[rt][1], s1i, g[2]));     \
      const float ni1 = fmaf(Wi[rt][1], s1r, fmaf( Wr[rt][1], s1i, g[3]));     \
      Sw[2 * rt]     = pk2(nr0, ni0);                                          \
      Sw[2 * rt + 1] = pk2(nr1, ni1);                                          \
    }                                                                          \
  }

  for (int c = 0; c < NCH; c += 2) {
    BODY(c, upA)
    BODY(c + 1, upB)
  }
#undef BODY
}

extern "C" void kernel_launch(void* const* d_in, const int* in_sizes, int n_in,
                              void* d_out, int out_size, void* d_ws, size_t ws_size,
                              hipStream_t stream)
{
  const float* u  = (const float*)d_in[0];
  const float* lr = (const float*)d_in[1];
  const float* li = (const float*)d_in[2];
  const float* cv = (const float*)d_in[3];
  const float* dv = (const float*)d_in[4];
  const float* dl = (const float*)d_in[5];
  float* yo = (float*)d_out;

  s4d_reg<<<dim3(Hh), dim3(256), 0, stream>>>(u, lr, li, cv, dv, dl, yo);
}